// Round 2
// baseline (378.597 us; speedup 1.0000x reference)
//
#include <hip/hip_runtime.h>
#include <stdint.h>

typedef unsigned short u16;
typedef __bf16 bf16x8 __attribute__((ext_vector_type(8)));
typedef float f32x4 __attribute__((ext_vector_type(4)));

#define SEQ    2048
#define NHEAD  16
#define DH     64
#define DMODEL 1024
#define NBH    64     // B*H

__device__ __forceinline__ u16 f2bf(float f){
  union { float f; uint32_t i; } v; v.f = f;
  uint32_t x = v.i;
  return (u16)((x + 0x7fffu + ((x >> 16) & 1u)) >> 16);
}
__device__ __forceinline__ float bf2f(u16 u){
  union { uint32_t i; float f; } v; v.i = ((uint32_t)u) << 16; return v.f;
}

typedef const __attribute__((address_space(1))) uint32_t* gas_t;
typedef __attribute__((address_space(3))) uint32_t* las_t;
__device__ __forceinline__ void async16(const void* g, void* l){
  __builtin_amdgcn_global_load_lds((gas_t)g, (las_t)l, 16, 0, 0);
}

// ---------------- f32 -> bf16 convert (vectorized, memory-bound) ------------
__global__ void cvt_f32_bf16(const float* __restrict__ src, u16* __restrict__ dst, int n){
  int t = (blockIdx.x*blockDim.x + threadIdx.x)*4;
  if (t >= n) return;
  float4 v = *(const float4*)(src + t);
  ushort4 o;
  o.x = f2bf(v.x); o.y = f2bf(v.y); o.z = f2bf(v.z); o.w = f2bf(v.w);
  *(ushort4*)(dst + t) = o;
}

// ---------------- GEMM: dst = A @ W^T + bias  (bf16 in, NT layout) ----------
// MODE 0: bf16 dst scattered to [B,H,S,Dh]; MODE 1: f32 dst linear [M][1024]
template<int MODE>
__global__ __launch_bounds__(256, 2)
void gemm_bt(const u16* __restrict__ A, const u16* __restrict__ W,
             const float* __restrict__ bias, void* __restrict__ dstv)
{
  __shared__ u16 Ab[128*32];
  __shared__ u16 Bb[128*32];
  const int tid = threadIdx.x;
  const int lane = tid & 63;
  const int w = tid >> 6, wr = w >> 1, wc = w & 1;
  const int m0 = blockIdx.y * 128;
  const int n0 = blockIdx.x * 128;
  const int c0 = lane & 15, g = lane >> 4;

  f32x4 acc[4][4] = {};

  const int sr = tid >> 2;          // staging row 0..63
  const int sc = (tid & 3) * 8;     // staging col (elements)
  const u16* ga = A + (size_t)(m0 + sr) * DMODEL + sc;
  const u16* gb = W + (size_t)(n0 + sr) * DMODEL + sc;
  u16* la = Ab + sr*32 + sc;
  u16* lb = Bb + sr*32 + sc;

  for (int k0 = 0; k0 < DMODEL; k0 += 32) {
    __syncthreads();
    async16(ga + k0,             la);
    async16(ga + k0 + 64*DMODEL, la + 64*32);
    async16(gb + k0,             lb);
    async16(gb + k0 + 64*DMODEL, lb + 64*32);
    __syncthreads();
    bf16x8 afr[4], bfr[4];
#pragma unroll
    for (int i=0;i<4;i++) afr[i] = *(const bf16x8*)(Ab + (wr*64 + i*16 + c0)*32 + g*8);
#pragma unroll
    for (int j=0;j<4;j++) bfr[j] = *(const bf16x8*)(Bb + (wc*64 + j*16 + c0)*32 + g*8);
#pragma unroll
    for (int i=0;i<4;i++)
#pragma unroll
      for (int j=0;j<4;j++)
        acc[i][j] = __builtin_amdgcn_mfma_f32_16x16x32_bf16(afr[i], bfr[j], acc[i][j], 0,0,0);
  }

#pragma unroll
  for (int i=0;i<4;i++){
    const int mbase = m0 + wr*64 + i*16 + g*4;
#pragma unroll
    for (int j=0;j<4;j++){
      const int n = n0 + wc*64 + j*16 + c0;
      const float bval = bias[n];
#pragma unroll
      for (int r=0;r<4;r++){
        const int mm = mbase + r;
        const float v = acc[i][j][r] + bval;
        if (MODE == 0) {
          const int b = mm >> 11, s = mm & (SEQ-1);
          const int h = n >> 6, dh = n & 63;
          ((u16*)dstv)[(((size_t)(b*NHEAD + h))*SEQ + s)*DH + dh] = f2bf(v);
        } else {
          ((float*)dstv)[(size_t)mm * DMODEL + n] = v;
        }
      }
    }
  }
}

// ---------------- RoPE table: [2048][64] = cos[0..31] | sin[0..31] ----------
__global__ void rope_table(float* __restrict__ tab){
  int t = blockIdx.x * blockDim.x + threadIdx.x;
  if (t >= SEQ*32) return;
  int s = t >> 5, j = t & 31;
  double freq = exp(-(double)(2*j) / 64.0 * log(10000.0));
  double ang = (double)s * freq;
  tab[s*64 + j]      = (float)cos(ang);
  tab[s*64 + 32 + j] = (float)sin(ang);
}

// ---------------- RoPE apply (in-place on q,k in [B,H,S,Dh], bf16) ----------
__global__ void rope_apply(u16* __restrict__ q, u16* __restrict__ k,
                           const float* __restrict__ tab){
  int t = blockIdx.x * blockDim.x + threadIdx.x;  // NBH*SEQ*8
  if (t >= NBH*SEQ*8) return;
  const int c  = t & 7;             // 4-pair chunk
  const int s  = (t >> 3) & (SEQ-1);
  const int bh = t >> 14;
  const size_t base = ((size_t)bh*SEQ + s) * DH;
  const int j0 = c * 4;
  const float* tc = tab + s*64 + j0;
  const float* ts = tab + s*64 + 32 + j0;
  union U4 { ushort4 v; u16 e[4]; };
  u16* ptrs[2] = { q + base, k + base };
#pragma unroll
  for (int m=0;m<2;m++){
    u16* p = ptrs[m];
    U4 lo, hi, olo, ohi;
    lo.v = *(const ushort4*)(p + j0);
    hi.v = *(const ushort4*)(p + 32 + j0);
#pragma unroll
    for (int e=0;e<4;e++){
      const float xl = bf2f(lo.e[e]), xh = bf2f(hi.e[e]);
      const float cs = tc[e], sn = ts[e];
      olo.e[e] = f2bf(xl*cs - xh*sn);
      ohi.e[e] = f2bf(xh*cs + xl*sn);
    }
    *(ushort4*)(p + j0)      = olo.v;
    *(ushort4*)(p + 32 + j0) = ohi.v;
  }
}

// ---------------- Flash attention, causal, QB=128 KB=64 ---------------------
__global__ __launch_bounds__(256, 2)
void attn_fwd(const u16* __restrict__ Q, const u16* __restrict__ K,
              const u16* __restrict__ V, u16* __restrict__ O)
{
  __shared__ u16 Kb[64*64];     // [kv][dh], XOR-swizzled via pre-swizzled source
  __shared__ u16 Vt[64*64];     // [dh][kv], XOR-swizzled
  __shared__ u16 Pb[128*64];    // [q][kv] per-wave regions, XOR-swizzled
  const int qt = blockIdx.x;
  const int bh = blockIdx.y;
  const int tid = threadIdx.x, lane = tid & 63, w = tid >> 6;
  const int c0 = lane & 15, g = lane >> 4;
  const size_t hb = (size_t)bh * SEQ * DH;
  const int qrow_base = qt*128 + w*32;

  // Q fragments hoisted to registers (A-operand: row=l&15, 8 contiguous dh)
  bf16x8 qf[2][2];
#pragma unroll
  for (int i=0;i<2;i++)
#pragma unroll
    for (int kc=0;kc<2;kc++)
      qf[i][kc] = *(const bf16x8*)(Q + hb + (size_t)(qrow_base + i*16 + c0)*DH + kc*32 + g*8);

  f32x4 oacc[2][4] = {};
  float mrun[2][4], lrun[2][4];
#pragma unroll
  for (int i=0;i<2;i++)
#pragma unroll
    for (int r=0;r<4;r++){ mrun[i][r] = -3.0e38f; lrun[i][r] = 0.f; }

  u16* Pw = Pb + w*32*64;

  // K staging: linear LDS dest + inverse-swizzled global source (involution)
  const int boff  = tid*16;
  const int sw1   = boff  ^ (((boff  >> 7)&7) << 4);
  const int boff2 = boff + 4096;
  const int sw2   = boff2 ^ (((boff2 >> 7)&7) << 4);
  const int rp = tid >> 3, dc = tid & 7;   // V-transpose roles
  union U4 { ushort4 v; u16 e[4]; };

  const int jt_end = 2*qt + 1;
  for (int jt = 0; jt <= jt_end; jt++){
    __syncthreads();
    const char* gk = (const char*)(K + hb + (size_t)jt*64*DH);
    async16(gk + sw1, (char*)Kb + boff);
    async16(gk + sw2, (char*)Kb + boff2);
    // V transpose into Vt[dh][kv] (pair kv,kv+1 -> one dword store)
    {
      const u16* gv = V + hb + (size_t)jt*64*DH;
      U4 v0a, v0b, v1a, v1b;
      v0a.v = *(const ushort4*)(gv + (2*rp  )*DH + dc*8);
      v0b.v = *(const ushort4*)(gv + (2*rp  )*DH + dc*8 + 4);
      v1a.v = *(const ushort4*)(gv + (2*rp+1)*DH + dc*8);
      v1b.v = *(const ushort4*)(gv + (2*rp+1)*DH + dc*8 + 4);
#pragma unroll
      for (int e=0;e<8;e++){
        const int row = dc*8 + e;                 // dh
        const int gbyte = row*128 + rp*4;         // kv*2 bytes, kv=2*rp
        const u16 a = (e<4) ? v0a.e[e] : v0b.e[e-4];
        const u16 b = (e<4) ? v1a.e[e] : v1b.e[e-4];
        const uint32_t pk = (uint32_t)a | ((uint32_t)b << 16);
        *(uint32_t*)((char*)Vt + (gbyte ^ ((row&7)<<4))) = pk;
      }
    }
    __syncthreads();

    if (jt*64 <= qrow_base + 31) {      // wave-uniform causal skip
      // ---- scores = Q K^T ----
      f32x4 sacc[2][4] = {};
#pragma unroll
      for (int kc=0;kc<2;kc++){
        bf16x8 kf[4];
#pragma unroll
        for (int j=0;j<4;j++){
          const int rr = j*16 + c0;
          const int gb2 = rr*128 + kc*64 + g*16;
          kf[j] = *(const bf16x8*)((const char*)Kb + (gb2 ^ ((rr&7)<<4)));
        }
#pragma unroll
        for (int i=0;i<2;i++)
#pragma unroll
          for (int j=0;j<4;j++)
            sacc[i][j] = __builtin_amdgcn_mfma_f32_16x16x32_bf16(qf[i][kc], kf[j], sacc[i][j], 0,0,0);
      }
      // ---- online softmax ----
#pragma unroll
      for (int i=0;i<2;i++){
#pragma unroll
        for (int r=0;r<4;r++){
          const int qrow = qrow_base + i*16 + g*4 + r;
          float mx = -3.0e38f;
#pragma unroll
          for (int j=0;j<4;j++){
            const int kv = jt*64 + j*16 + c0;
            float sv = sacc[i][j][r] * 0.125f;
            sv = (kv <= qrow) ? sv : -3.0e38f;
            sacc[i][j][r] = sv;
            mx = fmaxf(mx, sv);
          }
          mx = fmaxf(mx, __shfl_xor(mx, 1));
          mx = fmaxf(mx, __shfl_xor(mx, 2));
          mx = fmaxf(mx, __shfl_xor(mx, 4));
          mx = fmaxf(mx, __shfl_xor(mx, 8));
          const float mnew = fmaxf(mrun[i][r], mx);
          const float corr = __expf(mrun[i][r] - mnew);
          mrun[i][r] = mnew;
          float lsum = 0.f;
#pragma unroll
          for (int j=0;j<4;j++){
            const float p = __expf(sacc[i][j][r] - mnew);
            lsum += p;
            const int prow = i*16 + g*4 + r;
            const int pbyte = prow*128 + (j*16 + c0)*2;
            *(u16*)((char*)Pw + (pbyte ^ ((prow&7)<<4))) = f2bf(p);
          }
          lsum += __shfl_xor(lsum, 1);
          lsum += __shfl_xor(lsum, 2);
          lsum += __shfl_xor(lsum, 4);
          lsum += __shfl_xor(lsum, 8);
          lrun[i][r] = lrun[i][r]*corr + lsum;
#pragma unroll
          for (int d=0; d<4; d++) oacc[i][d][r] *= corr;
        }
      }
      asm volatile("s_waitcnt lgkmcnt(0)" ::: "memory");  // wave-private P wr->rd
      // ---- O += P V ----
#pragma unroll
      for (int kc=0;kc<2;kc++){
        bf16x8 pa[2];
#pragma unroll
        for (int i=0;i<2;i++){
          const int rr = i*16 + c0;
          const int gb2 = rr*128 + kc*64 + g*16;
          pa[i] = *(const bf16x8*)((const char*)Pw + (gb2 ^ ((rr&7)<<4)));
        }
#pragma unroll
        for (int d=0; d<4; d++){
          const int rr = d*16 + c0;
          const int gb2 = rr*128 + kc*64 + g*16;
          const bf16x8 vf = *(const bf16x8*)((const char*)Vt + (gb2 ^ ((rr&7)<<4)));
#pragma unroll
          for (int i=0;i<2;i++)
            oacc[i][d] = __builtin_amdgcn_mfma_f32_16x16x32_bf16(pa[i], vf, oacc[i][d], 0,0,0);
        }
      }
    }
  }

  // write attn output to [B,S,H*Dh] (bf16)
  const int b = bh >> 4, h = bh & 15;
#pragma unroll
  for (int i=0;i<2;i++){
#pragma unroll
    for (int r=0;r<4;r++){
      const float inv = 1.0f / lrun[i][r];
      const int mm = qrow_base + i*16 + g*4 + r;
#pragma unroll
      for (int d=0; d<4; d++)
        O[(((size_t)b*SEQ + mm)*NHEAD + h)*DH + d*16 + c0] = f2bf(oacc[i][d][r] * inv);
    }
  }
}

// ---------------------------------------------------------------------------
extern "C" void kernel_launch(void* const* d_in, const int* in_sizes, int n_in,
                              void* d_out, int out_size, void* d_ws, size_t ws_size,
                              hipStream_t stream)
{
  const float* x  = (const float*)d_in[0];
  const float* Wq = (const float*)d_in[1];
  const float* bq = (const float*)d_in[2];
  const float* Wk = (const float*)d_in[3];
  const float* bk = (const float*)d_in[4];
  const float* Wv = (const float*)d_in[5];
  const float* bv = (const float*)d_in[6];
  const float* Wo = (const float*)d_in[7];
  const float* bo = (const float*)d_in[8];
  // d_in[9]: causal mask (int32) — implemented analytically, not read.

  const size_t MB = 1024*1024;
  char* ws = (char*)d_ws;
  // ws layout (40.5 MB):
  u16*  xb  = (u16*)(ws);                 // [0,16MB)  x in bf16; dead after projections
  u16*  aw  = (u16*)(ws);                 // reuses xb region for attn output
  u16*  vw  = (u16*)(ws + 16*MB);         // [16,32MB) V in [B,H,S,Dh]
  u16*  wqb = (u16*)(ws + 32*MB);         // 2MB each
  u16*  wkb = (u16*)(ws + 34*MB);
  u16*  wvb = (u16*)(ws + 36*MB);
  u16*  wob = (u16*)(ws + 38*MB);
  float* tab = (float*)(ws + 40*MB);      // 512KB
  // d_out (32MB f32) doubles as scratch for q/k (bf16, dead before final GEMM)
  u16*  qw = (u16*)d_out;                 // [0,16MB)
  u16*  kw = (u16*)d_out + 8*MB;          // [16,32MB)  (8M u16 elements)

  const int NX = 4*SEQ*DMODEL;   // 8,388,608
  const int NW = DMODEL*DMODEL;  // 1,048,576
  cvt_f32_bf16<<<dim3(NX/1024), dim3(256), 0, stream>>>(x,  xb,  NX);
  cvt_f32_bf16<<<dim3(NW/1024), dim3(256), 0, stream>>>(Wq, wqb, NW);
  cvt_f32_bf16<<<dim3(NW/1024), dim3(256), 0, stream>>>(Wk, wkb, NW);
  cvt_f32_bf16<<<dim3(NW/1024), dim3(256), 0, stream>>>(Wv, wvb, NW);
  cvt_f32_bf16<<<dim3(NW/1024), dim3(256), 0, stream>>>(Wo, wob, NW);

  rope_table<<<dim3(256), dim3(256), 0, stream>>>(tab);

  dim3 gg(8, 64);
  gemm_bt<0><<<gg, dim3(256), 0, stream>>>(xb, wqb, bq, qw);
  gemm_bt<0><<<gg, dim3(256), 0, stream>>>(xb, wkb, bk, kw);
  gemm_bt<0><<<gg, dim3(256), 0, stream>>>(xb, wvb, bv, vw);

  rope_apply<<<dim3(4096), dim3(256), 0, stream>>>(qw, kw, tab);

  attn_fwd<<<dim3(16, 64), dim3(256), 0, stream>>>(qw, kw, vw, aw);

  gemm_bt<1><<<gg, dim3(256), 0, stream>>>(aw, wob, bo, d_out);
}